// Round 1
// baseline (8837.283 us; speedup 1.0000x reference)
//
#include <hip/hip_runtime.h>
#include <math.h>

#define HID   1024
#define IN_D  600
#define BATCH 2048
#define TSTEP 20
#define G3    (3 * HID)   // 3072

// C[M, G3] = A[M,K] * B[G3,K]^T   (both operands K-contiguous row-major)
// Tile 64x64, 256 threads, 4x4 acc per thread. K must be a multiple of BK.
template <int BK>
__global__ __launch_bounds__(256) void gemm_abt(const float* __restrict__ A, int lda,
                                                const float* __restrict__ B, int ldb,
                                                float* __restrict__ C, int K) {
    __shared__ float sA[BK][65];
    __shared__ float sB[BK][65];
    constexpr int V = BK / 4;  // floats loaded per thread per operand (4 or 2)

    const int tid  = threadIdx.x;
    const int m0   = blockIdx.y * 64;
    const int n0   = blockIdx.x * 64;
    const int arow = tid >> 2;         // 0..63
    const int acol = (tid & 3) * V;    // k offset within tile
    const int ty   = tid >> 4;         // 0..15
    const int tx   = tid & 15;         // 0..15

    float acc[4][4] = {};

    const float* Ar = A + (size_t)(m0 + arow) * lda + acol;
    const float* Br = B + (size_t)(n0 + arow) * ldb + acol;

    for (int k0 = 0; k0 < K; k0 += BK) {
        if constexpr (V == 4) {
            float4 av = *(const float4*)(Ar + k0);
            float4 bv = *(const float4*)(Br + k0);
            sA[acol + 0][arow] = av.x; sA[acol + 1][arow] = av.y;
            sA[acol + 2][arow] = av.z; sA[acol + 3][arow] = av.w;
            sB[acol + 0][arow] = bv.x; sB[acol + 1][arow] = bv.y;
            sB[acol + 2][arow] = bv.z; sB[acol + 3][arow] = bv.w;
        } else {
            float2 av = *(const float2*)(Ar + k0);
            float2 bv = *(const float2*)(Br + k0);
            sA[acol + 0][arow] = av.x; sA[acol + 1][arow] = av.y;
            sB[acol + 0][arow] = bv.x; sB[acol + 1][arow] = bv.y;
        }
        __syncthreads();
#pragma unroll
        for (int kk = 0; kk < BK; ++kk) {
            float a0 = sA[kk][ty * 4 + 0], a1 = sA[kk][ty * 4 + 1];
            float a2 = sA[kk][ty * 4 + 2], a3 = sA[kk][ty * 4 + 3];
            float b0 = sB[kk][tx * 4 + 0], b1 = sB[kk][tx * 4 + 1];
            float b2 = sB[kk][tx * 4 + 2], b3 = sB[kk][tx * 4 + 3];
            acc[0][0] += a0 * b0; acc[0][1] += a0 * b1; acc[0][2] += a0 * b2; acc[0][3] += a0 * b3;
            acc[1][0] += a1 * b0; acc[1][1] += a1 * b1; acc[1][2] += a1 * b2; acc[1][3] += a1 * b3;
            acc[2][0] += a2 * b0; acc[2][1] += a2 * b1; acc[2][2] += a2 * b2; acc[2][3] += a2 * b3;
            acc[3][0] += a3 * b0; acc[3][1] += a3 * b1; acc[3][2] += a3 * b2; acc[3][3] += a3 * b3;
        }
        __syncthreads();
    }

#pragma unroll
    for (int i = 0; i < 4; ++i) {
        float4 v;
        v.x = acc[i][0]; v.y = acc[i][1]; v.z = acc[i][2]; v.w = acc[i][3];
        *(float4*)(C + (size_t)(m0 + ty * 4 + i) * G3 + n0 + tx * 4) = v;
    }
}

// GRU gate fusion: per (b, j)
// r = sigmoid(gx_r + bih_r + gh_r + bhh_r)
// i = sigmoid(gx_i + bih_i + gh_i + bhh_i)
// n = tanh((gx_n + bih_n) + r * (gh_n + bhh_n))
// hy = n + i * (h - n)
__global__ __launch_bounds__(256) void gru_pointwise(const float* __restrict__ gx,
                                                     const float* __restrict__ gh,
                                                     const float* __restrict__ b_ih,
                                                     const float* __restrict__ b_hh,
                                                     const float* __restrict__ h_in,
                                                     float* __restrict__ h_out) {
    int idx = blockIdx.x * blockDim.x + threadIdx.x;  // b * HID + j
    int b = idx >> 10;
    int j = idx & (HID - 1);

    const float* gxr = gx + (size_t)b * G3;
    const float* ghr = gh + (size_t)b * G3;

    float pre_r = gxr[j] + b_ih[j] + ghr[j] + b_hh[j];
    float pre_i = gxr[HID + j] + b_ih[HID + j] + ghr[HID + j] + b_hh[HID + j];
    float gxn   = gxr[2 * HID + j] + b_ih[2 * HID + j];
    float ghn   = ghr[2 * HID + j] + b_hh[2 * HID + j];

    float r = 1.0f / (1.0f + __expf(-pre_r));
    float i = 1.0f / (1.0f + __expf(-pre_i));
    float n = tanhf(gxn + r * ghn);

    float h = h_in[idx];
    h_out[idx] = n + i * (h - n);
}

extern "C" void kernel_launch(void* const* d_in, const int* in_sizes, int n_in,
                              void* d_out, int out_size, void* d_ws, size_t ws_size,
                              hipStream_t stream) {
    const float* x    = (const float*)d_in[0];  // [B, T, IN_D]
    const float* W_ih = (const float*)d_in[1];  // [3H, IN_D]
    const float* b_ih = (const float*)d_in[2];  // [3H]
    const float* W_hh = (const float*)d_in[3];  // [3H, HID]
    const float* b_hh = (const float*)d_in[4];  // [3H]
    float* out = (float*)d_out;                 // [B, HID]

    float* gx = (float*)d_ws;                       // [B, 3H]
    float* gh = gx + (size_t)BATCH * G3;            // [B, 3H]
    float* h  = gh + (size_t)BATCH * G3;            // [B, HID]

    // h0 = 0 (ws is poisoned each call)
    hipMemsetAsync(h, 0, (size_t)BATCH * HID * sizeof(float), stream);

    dim3 ggrid(G3 / 64, BATCH / 64);  // (48, 32)
    int pw_blocks = (BATCH * HID) / 256;  // 8192

    for (int t = 0; t < TSTEP; ++t) {
        // gx = x_t @ W_ih^T   (K = 600, multiple of 8)
        gemm_abt<8><<<ggrid, 256, 0, stream>>>(x + (size_t)t * IN_D, TSTEP * IN_D,
                                               W_ih, IN_D, gx, IN_D);
        // gh = h @ W_hh^T     (K = 1024, multiple of 16)
        gemm_abt<16><<<ggrid, 256, 0, stream>>>(h, HID, W_hh, HID, gh, HID);
        // gate fusion + state update (in-place safe; last step writes d_out)
        float* h_next = (t == TSTEP - 1) ? out : h;
        gru_pointwise<<<pw_blocks, 256, 0, stream>>>(gx, gh, b_ih, b_hh, h, h_next);
    }
}

// Round 2
// 1955.145 us; speedup vs baseline: 4.5200x; 4.5200x over previous
//
#include <hip/hip_runtime.h>
#include <hip/hip_bf16.h>
#include <math.h>

#define HID   1024
#define IN_D  600
#define IN_DP 608      // 600 padded to multiple of 32
#define BATCH 2048
#define TSTEP 20
#define G3    3072

typedef __attribute__((ext_vector_type(8))) short bf16x8;
typedef __attribute__((ext_vector_type(4))) float f32x4;

#define GLB(p) ((const __attribute__((address_space(1))) void*)(p))
#define LDS(p) ((__attribute__((address_space(3))) void*)(p))

__device__ __forceinline__ short f2bf(float f) {
    __hip_bfloat16 b = __float2bfloat16(f);
    return *(short*)&b;
}

// C[M,N-tile] = A[M,K] * B[N,K]^T, A/B K-contiguous. bf16 MFMA 16x16x32.
// 128x128 tile, 256 threads = 4 waves (2x2), 4x4 MFMA frags per wave, BK=32.
// A_BF16: A is bf16, staged via global_load_lds. else: A fp32, staged with
//         guarded float4 load + cvt (k >= Kreal -> 0).
// EPI==0: C0[m*G3 + n] = acc                  (input projection -> gx)
// EPI==1: n<2048: C0[m*G3+n] += acc (gx RMW); n>=2048: C1[m*1024+n-2048] = acc
template <int EPI, bool A_BF16>
__global__ __launch_bounds__(256) void gemm_mfma(const void* __restrict__ Av, int lda,
                                                 const short* __restrict__ B, int ldb,
                                                 float* __restrict__ C0,
                                                 float* __restrict__ C1,
                                                 int K, int Kreal) {
    __shared__ short sA[128 * 32];
    __shared__ short sB[128 * 32];

    const int tid  = threadIdx.x;
    const int wave = tid >> 6;
    const int lane = tid & 63;
    const int m0 = blockIdx.y * 128;
    const int n0 = blockIdx.x * 128;
    const int wm = (wave >> 1) * 64;
    const int wn = (wave & 1) * 64;

    // staging maps (bf16 path): round j in {0,1}: row = j*64 + tid/4, col = (tid&3)*8
    const int srow = tid >> 2;
    const int scol = (tid & 3) * 8;
    // fp32-A staging map: round j in {0..3}: row = j*32 + tid/8, col = (tid&7)*4
    const int frow = tid >> 3;
    const int fcol = (tid & 7) * 4;

    const int fm = lane & 15;   // frag row (m or n)
    const int fq = lane >> 4;   // frag k-quad: k = fq*8..fq*8+7

    f32x4 acc[4][4] = {};

    for (int k0 = 0; k0 < K; k0 += 32) {
        // ---- B tile (bf16, async direct-to-LDS) ----
#pragma unroll
        for (int j = 0; j < 2; ++j) {
            const short* g = B + (size_t)(n0 + j * 64 + srow) * ldb + k0 + scol;
            __builtin_amdgcn_global_load_lds(GLB(g), LDS(sB + j * 2048 + wave * 512), 16, 0, 0);
        }
        // ---- A tile ----
        if constexpr (A_BF16) {
            const short* Ab = (const short*)Av;
#pragma unroll
            for (int j = 0; j < 2; ++j) {
                const short* g = Ab + (size_t)(m0 + j * 64 + srow) * lda + k0 + scol;
                __builtin_amdgcn_global_load_lds(GLB(g), LDS(sA + j * 2048 + wave * 512), 16, 0, 0);
            }
        } else {
            const float* Af = (const float*)Av;
#pragma unroll
            for (int j = 0; j < 4; ++j) {
                int row = j * 32 + frow;
                int k = k0 + fcol;
                float4 v = make_float4(0.f, 0.f, 0.f, 0.f);
                if (k < Kreal) v = *(const float4*)(Af + (size_t)(m0 + row) * lda + k);
                short4 sv;
                sv.x = f2bf(v.x); sv.y = f2bf(v.y); sv.z = f2bf(v.z); sv.w = f2bf(v.w);
                *(short4*)(sA + row * 32 + fcol) = sv;
            }
        }
        __syncthreads();

        bf16x8 af[4], bf[4];
#pragma unroll
        for (int mi = 0; mi < 4; ++mi)
            af[mi] = *(const bf16x8*)(sA + (wm + mi * 16 + fm) * 32 + fq * 8);
#pragma unroll
        for (int ni = 0; ni < 4; ++ni)
            bf[ni] = *(const bf16x8*)(sB + (wn + ni * 16 + fm) * 32 + fq * 8);
#pragma unroll
        for (int mi = 0; mi < 4; ++mi)
#pragma unroll
            for (int ni = 0; ni < 4; ++ni)
                acc[mi][ni] = __builtin_amdgcn_mfma_f32_16x16x32_bf16(af[mi], bf[ni], acc[mi][ni], 0, 0, 0);
        __syncthreads();
    }

    // epilogue: D row (m) = fq*4 + r, col (n) = fm
#pragma unroll
    for (int mi = 0; mi < 4; ++mi) {
#pragma unroll
        for (int ni = 0; ni < 4; ++ni) {
            int gn = n0 + wn + ni * 16 + fm;
#pragma unroll
            for (int r = 0; r < 4; ++r) {
                int gm = m0 + wm + mi * 16 + fq * 4 + r;
                float v = acc[mi][ni][r];
                if constexpr (EPI == 0) {
                    C0[(size_t)gm * G3 + gn] = v;
                } else {
                    if (gn < 2048) C0[(size_t)gm * G3 + gn] += v;
                    else           C1[(size_t)gm * 1024 + (gn - 2048)] = v;
                }
            }
        }
    }
}

// GRU gates. gx already holds x-proj with h-proj accumulated for r/i chunks;
// ghn holds the h-side n-chunk separately.
__global__ __launch_bounds__(256) void gru_pointwise(const float* __restrict__ gx,
                                                     const float* __restrict__ ghn,
                                                     const float* __restrict__ b_ih,
                                                     const float* __restrict__ b_hh,
                                                     float* __restrict__ hf,
                                                     short* __restrict__ hb,
                                                     float* __restrict__ out,
                                                     int last) {
    int idx = blockIdx.x * blockDim.x + threadIdx.x;  // b*HID + j
    int b = idx >> 10;
    int j = idx & (HID - 1);
    const float* g = gx + (size_t)b * G3;

    float pre_r = g[j] + b_ih[j] + b_hh[j];
    float pre_i = g[HID + j] + b_ih[HID + j] + b_hh[HID + j];
    float xn    = g[2 * HID + j] + b_ih[2 * HID + j];
    float hn    = ghn[idx] + b_hh[2 * HID + j];

    float r = 1.0f / (1.0f + __expf(-pre_r));
    float i = 1.0f / (1.0f + __expf(-pre_i));
    float n = tanhf(xn + r * hn);

    float h  = hf[idx];
    float hy = n + i * (h - n);
    hf[idx] = hy;
    hb[idx] = f2bf(hy);
    if (last) out[idx] = hy;
}

// W_ih [3072,600] fp32 -> [3072,608] bf16 zero-padded
__global__ __launch_bounds__(256) void cvt_wih(const float* __restrict__ W, short* __restrict__ Wb) {
    int r = blockIdx.x;
    for (int c = threadIdx.x; c < IN_DP; c += 256) {
        float v = (c < IN_D) ? W[(size_t)r * IN_D + c] : 0.f;
        Wb[(size_t)r * IN_DP + c] = f2bf(v);
    }
}

__global__ __launch_bounds__(256) void cvt_flat(const float* __restrict__ W, short* __restrict__ Wb, int n) {
    int i = blockIdx.x * 256 + threadIdx.x;
    if (i < n) Wb[i] = f2bf(W[i]);
}

extern "C" void kernel_launch(void* const* d_in, const int* in_sizes, int n_in,
                              void* d_out, int out_size, void* d_ws, size_t ws_size,
                              hipStream_t stream) {
    const float* x    = (const float*)d_in[0];  // [B, T, IN_D]
    const float* W_ih = (const float*)d_in[1];  // [3H, IN_D]
    const float* b_ih = (const float*)d_in[2];
    const float* W_hh = (const float*)d_in[3];  // [3H, HID]
    const float* b_hh = (const float*)d_in[4];
    float* out = (float*)d_out;                 // [B, HID]

    char* p = (char*)d_ws;
    float* gx     = (float*)p;  p += (size_t)BATCH * G3 * 4;          // 25.2 MB
    float* ghn    = (float*)p;  p += (size_t)BATCH * HID * 4;         //  8.4 MB
    float* hf     = (float*)p;  p += (size_t)BATCH * HID * 4;         //  8.4 MB
    short* hb     = (short*)p;  p += (size_t)BATCH * HID * 2;         //  4.2 MB
    short* Wih_bf = (short*)p;  p += (size_t)G3 * IN_DP * 2;          //  3.7 MB
    short* Whh_bf = (short*)p;  p += (size_t)G3 * HID * 2;            //  6.3 MB
    // total ~56.2 MB

    // one-time per call: weight conversion + h0 = 0
    cvt_wih<<<G3, 256, 0, stream>>>(W_ih, Wih_bf);
    cvt_flat<<<(G3 * HID + 255) / 256, 256, 0, stream>>>(W_hh, Whh_bf, G3 * HID);
    hipMemsetAsync(hf, 0, (size_t)BATCH * HID * 4, stream);
    hipMemsetAsync(hb, 0, (size_t)BATCH * HID * 2, stream);

    dim3 ggrid(G3 / 128, BATCH / 128);   // (24, 16)
    int pw_blocks = (BATCH * HID) / 256; // 8192

    for (int t = 0; t < TSTEP; ++t) {
        // gx = x_t @ W_ih^T  (A fp32 staged+cvt, K padded 600->608)
        gemm_mfma<0, false><<<ggrid, 256, 0, stream>>>(x + (size_t)t * IN_D, TSTEP * IN_D,
                                                       Wih_bf, IN_DP, gx, nullptr, IN_DP, IN_D);
        // r/i: gx += h @ W_hh^T ; n-chunk -> ghn
        gemm_mfma<1, true><<<ggrid, 256, 0, stream>>>(hb, HID, Whh_bf, HID, gx, ghn, HID, HID);
        gru_pointwise<<<pw_blocks, 256, 0, stream>>>(gx, ghn, b_ih, b_hh, hf, hb, out,
                                                     t == TSTEP - 1 ? 1 : 0);
    }
}

// Round 3
// 1441.166 us; speedup vs baseline: 6.1320x; 1.3566x over previous
//
#include <hip/hip_runtime.h>
#include <hip/hip_bf16.h>
#include <math.h>

#define HID   1024
#define IN_D  600
#define IN_DP 608      // 600 padded to multiple of 32
#define BATCH 2048
#define TSTEP 20
#define BT    (BATCH * TSTEP)   // 40960
#define G3    3072

typedef __attribute__((ext_vector_type(8))) short bf16x8;
typedef __attribute__((ext_vector_type(4))) float f32x4;

#define GLB(p) ((const __attribute__((address_space(1))) void*)(p))
#define LDS(p) ((__attribute__((address_space(3))) void*)(p))

__device__ __forceinline__ short f2bf(float f) {
    __hip_bfloat16 b = __float2bfloat16(f);
    return *(short*)&b;
}
__device__ __forceinline__ float bf2f(short s) {
    __hip_bfloat16 b = *(__hip_bfloat16*)&s;
    return __bfloat162float(b);
}

// ---------------------------------------------------------------------------
// Big input projection: gx[m, n] = x[m, :] . W_ih[n, :] + b_ih[n]
// A = x fp32 [BT, 600] (lda=600, K padded to 608, staged w/ guard+cvt)
// B = Wih_bf [3072, 608]
// n < 2048  -> gxri[m*2048 + n]          (bf16, r/i gates)
// n >= 2048 -> gxn [m*1024 + n - 2048]   (fp32, n gate — tanh-sensitive)
// 128x128 tile, 256 thr = 4 waves (2x2), 4x4 16x16x32 bf16 MFMA frags/wave.
// ---------------------------------------------------------------------------
__global__ __launch_bounds__(256) void gemm_input(const float* __restrict__ X,
                                                  const short* __restrict__ B,
                                                  const float* __restrict__ b_ih,
                                                  short* __restrict__ gxri,
                                                  float* __restrict__ gxn) {
    __shared__ short sA[128 * 32];
    __shared__ short sB[128 * 32];

    const int tid  = threadIdx.x;
    const int wave = tid >> 6;
    const int lane = tid & 63;
    const int m0 = blockIdx.y * 128;
    const int n0 = blockIdx.x * 128;
    const int wm = (wave >> 1) * 64;
    const int wn = (wave & 1) * 64;

    const int srow = tid >> 2;        // bf16 staging: row within 2 rounds
    const int scol = (tid & 3) * 8;
    const int frow = tid >> 3;        // fp32 staging: row within 4 rounds
    const int fcol = (tid & 7) * 4;

    const int fm = lane & 15;
    const int fq = lane >> 4;

    f32x4 acc[4][4] = {};

    for (int k0 = 0; k0 < IN_DP; k0 += 32) {
#pragma unroll
        for (int j = 0; j < 2; ++j) {
            const short* g = B + (size_t)(n0 + j * 64 + srow) * IN_DP + k0 + scol;
            __builtin_amdgcn_global_load_lds(GLB(g), LDS(sB + j * 2048 + wave * 512), 16, 0, 0);
        }
#pragma unroll
        for (int j = 0; j < 4; ++j) {
            int row = j * 32 + frow;
            int k = k0 + fcol;
            float4 v = make_float4(0.f, 0.f, 0.f, 0.f);
            if (k < IN_D) v = *(const float4*)(X + (size_t)(m0 + row) * IN_D + k);
            short4 sv;
            sv.x = f2bf(v.x); sv.y = f2bf(v.y); sv.z = f2bf(v.z); sv.w = f2bf(v.w);
            *(short4*)(sA + row * 32 + fcol) = sv;
        }
        __syncthreads();

        bf16x8 af[4], bf[4];
#pragma unroll
        for (int mi = 0; mi < 4; ++mi)
            af[mi] = *(const bf16x8*)(sA + (wm + mi * 16 + fm) * 32 + fq * 8);
#pragma unroll
        for (int ni = 0; ni < 4; ++ni)
            bf[ni] = *(const bf16x8*)(sB + (wn + ni * 16 + fm) * 32 + fq * 8);
#pragma unroll
        for (int mi = 0; mi < 4; ++mi)
#pragma unroll
            for (int ni = 0; ni < 4; ++ni)
                acc[mi][ni] = __builtin_amdgcn_mfma_f32_16x16x32_bf16(af[mi], bf[ni], acc[mi][ni], 0, 0, 0);
        __syncthreads();
    }

#pragma unroll
    for (int ni = 0; ni < 4; ++ni) {
        int gn = n0 + wn + ni * 16 + fm;
        float bias = b_ih[gn];
#pragma unroll
        for (int mi = 0; mi < 4; ++mi) {
#pragma unroll
            for (int r = 0; r < 4; ++r) {
                int gm = m0 + wm + mi * 16 + fq * 4 + r;
                float v = acc[mi][ni][r] + bias;
                if (gn < 2048) gxri[(size_t)gm * 2048 + gn] = f2bf(v);
                else           gxn[(size_t)gm * 1024 + (gn - 2048)] = v;
            }
        }
    }
}

// ---------------------------------------------------------------------------
// Fused recurrent step: per block, a 128(batch) x 32(hidden) tile of ALL 3
// gate projections gh = h @ W_hh^T, then full GRU gate math + state update.
// Grid (1024/32, 2048/128) = (32, 16) = 512 blocks. 4 waves 2x2:
// wave m-half {0,64}, n-half {0,16}. acc[gate][mi] = 3*4 f32x4.
// hb ping-pong across steps (blocks read all cols of h_in, write own tile).
// ---------------------------------------------------------------------------
__global__ __launch_bounds__(256) void gru_step(const short* __restrict__ hb_in,
                                                const short* __restrict__ Whh,
                                                const short* __restrict__ gxri,
                                                const float* __restrict__ gxn,
                                                const float* __restrict__ b_hh,
                                                float* __restrict__ hf,
                                                short* __restrict__ hb_out,
                                                float* __restrict__ out,
                                                int t, int last) {
    __shared__ short sA[128 * 32];
    __shared__ short sB[3 * 32 * 32];

    const int tid  = threadIdx.x;
    const int wave = tid >> 6;
    const int lane = tid & 63;
    const int m0 = blockIdx.y * 128;   // batch rows
    const int j0 = blockIdx.x * 32;    // hidden cols
    const int wm = (wave >> 1) * 64;
    const int wn = (wave & 1) * 16;
    const int fm = lane & 15;
    const int fq = lane >> 4;

    f32x4 acc[3][4] = {};   // [gate][m-frag]

    for (int k0 = 0; k0 < HID; k0 += 32) {
        // A tile: hb_in[m0..m0+127][k0..k0+31]
#pragma unroll
        for (int j = 0; j < 2; ++j) {
            const short* g = hb_in + (size_t)(m0 + j * 64 + (tid >> 2)) * HID + k0 + (tid & 3) * 8;
            __builtin_amdgcn_global_load_lds(GLB(g), LDS(sA + j * 2048 + wave * 512), 16, 0, 0);
        }
        // B tiles: gate g rows Whh[g*1024 + j0 .. +31][k0..k0+31]
        // 6 wave-units of 16 rows; unit u -> gate u>>1, row-half u&1
        {
            int u = wave;
            const short* g = Whh + (size_t)((u >> 1) * HID + j0 + (u & 1) * 16 + (lane >> 2)) * HID + k0 + (lane & 3) * 8;
            __builtin_amdgcn_global_load_lds(GLB(g), LDS(sB + u * 512), 16, 0, 0);
        }
        if (wave < 2) {
            int u = 4 + wave;
            const short* g = Whh + (size_t)((u >> 1) * HID + j0 + (u & 1) * 16 + (lane >> 2)) * HID + k0 + (lane & 3) * 8;
            __builtin_amdgcn_global_load_lds(GLB(g), LDS(sB + u * 512), 16, 0, 0);
        }
        __syncthreads();

        bf16x8 af[4], bg[3];
#pragma unroll
        for (int mi = 0; mi < 4; ++mi)
            af[mi] = *(const bf16x8*)(sA + (wm + mi * 16 + fm) * 32 + fq * 8);
#pragma unroll
        for (int g = 0; g < 3; ++g)
            bg[g] = *(const bf16x8*)(sB + g * 1024 + (wn + fm) * 32 + fq * 8);
#pragma unroll
        for (int g = 0; g < 3; ++g)
#pragma unroll
            for (int mi = 0; mi < 4; ++mi)
                acc[g][mi] = __builtin_amdgcn_mfma_f32_16x16x32_bf16(af[mi], bg[g], acc[g][mi], 0, 0, 0);
        __syncthreads();
    }

    // Epilogue: gate math + update. D frag: row = fq*4 + r, col = fm.
    const int gj = j0 + wn + fm;   // hidden index 0..1023
    const float bh_r = b_hh[gj];
    const float bh_i = b_hh[HID + gj];
    const float bh_n = b_hh[2 * HID + gj];

#pragma unroll
    for (int mi = 0; mi < 4; ++mi) {
#pragma unroll
        for (int r = 0; r < 4; ++r) {
            int gm = m0 + wm + mi * 16 + fq * 4 + r;          // batch row
            size_t xrow = (size_t)gm * TSTEP + t;             // [B, T] order
            float xr = bf2f(gxri[xrow * 2048 + gj]);
            float xi = bf2f(gxri[xrow * 2048 + HID + gj]);
            float xn = gxn[xrow * 1024 + gj];

            float hr = acc[0][mi][r] + bh_r;
            float hi = acc[1][mi][r] + bh_i;
            float hn = acc[2][mi][r] + bh_n;

            float rg = 1.0f / (1.0f + __expf(-(xr + hr)));
            float ig = 1.0f / (1.0f + __expf(-(xi + hi)));
            float ng = tanhf(xn + rg * hn);

            size_t idx = (size_t)gm * HID + gj;
            float h  = hf[idx];
            float hy = ng + ig * (h - ng);
            hf[idx] = hy;
            hb_out[idx] = f2bf(hy);
            if (last) out[idx] = hy;
        }
    }
}

// W_ih [3072,600] fp32 -> [3072,608] bf16 zero-padded
__global__ __launch_bounds__(256) void cvt_wih(const float* __restrict__ W, short* __restrict__ Wb) {
    int r = blockIdx.x;
    for (int c = threadIdx.x; c < IN_DP; c += 256) {
        float v = (c < IN_D) ? W[(size_t)r * IN_D + c] : 0.f;
        Wb[(size_t)r * IN_DP + c] = f2bf(v);
    }
}

__global__ __launch_bounds__(256) void cvt_flat(const float* __restrict__ W, short* __restrict__ Wb, int n) {
    int i = blockIdx.x * 256 + threadIdx.x;
    if (i < n) Wb[i] = f2bf(W[i]);
}

extern "C" void kernel_launch(void* const* d_in, const int* in_sizes, int n_in,
                              void* d_out, int out_size, void* d_ws, size_t ws_size,
                              hipStream_t stream) {
    const float* x    = (const float*)d_in[0];  // [B, T, IN_D] = [BT, 600]
    const float* W_ih = (const float*)d_in[1];  // [3H, IN_D]
    const float* b_ih = (const float*)d_in[2];
    const float* W_hh = (const float*)d_in[3];  // [3H, HID]
    const float* b_hh = (const float*)d_in[4];
    float* out = (float*)d_out;                 // [B, HID]

    char* p = (char*)d_ws;
    short* gxri   = (short*)p;  p += (size_t)BT * 2048 * 2;     // 167.8 MB
    float* gxn    = (float*)p;  p += (size_t)BT * 1024 * 4;     // 167.8 MB
    float* hf     = (float*)p;  p += (size_t)BATCH * HID * 4;   //   8.4 MB
    short* hb0    = (short*)p;  p += (size_t)BATCH * HID * 2;   //   4.2 MB
    short* hb1    = (short*)p;  p += (size_t)BATCH * HID * 2;   //   4.2 MB
    short* Wih_bf = (short*)p;  p += (size_t)G3 * IN_DP * 2;    //   3.7 MB
    short* Whh_bf = (short*)p;  p += (size_t)G3 * HID * 2;      //   6.3 MB
    // total ~362 MB (ws ~393 MB)

    cvt_wih<<<G3, 256, 0, stream>>>(W_ih, Wih_bf);
    cvt_flat<<<(G3 * HID + 255) / 256, 256, 0, stream>>>(W_hh, Whh_bf, G3 * HID);
    hipMemsetAsync(hf, 0, (size_t)BATCH * HID * 4, stream);
    hipMemsetAsync(hb0, 0, (size_t)BATCH * HID * 2, stream);

    // One big input projection over all timesteps: M = 40960
    dim3 igrid(G3 / 128, BT / 128);   // (24, 320)
    gemm_input<<<igrid, 256, 0, stream>>>(x, Wih_bf, b_ih, gxri, gxn);

    // 20 fused recurrent steps
    dim3 rgrid(HID / 32, BATCH / 128);  // (32, 16) = 512 blocks
    for (int t = 0; t < TSTEP; ++t) {
        const short* hin = (t & 1) ? hb1 : hb0;
        short* hout      = (t & 1) ? hb0 : hb1;
        gru_step<<<rgrid, 256, 0, stream>>>(hin, Whh_bf, gxri, gxn, b_hh,
                                            hf, hout, out, t, t == TSTEP - 1 ? 1 : 0);
    }
}

// Round 4
// 1180.751 us; speedup vs baseline: 7.4845x; 1.2206x over previous
//
#include <hip/hip_runtime.h>
#include <hip/hip_bf16.h>
#include <math.h>

#define HID   1024
#define IN_D  600
#define IN_DP 608      // 600 padded to multiple of 32
#define BATCH 2048
#define TSTEP 20
#define BT    (BATCH * TSTEP)   // 40960
#define G3    3072

typedef __attribute__((ext_vector_type(8))) short bf16x8;
typedef __attribute__((ext_vector_type(4))) float f32x4;

#define GLB(p) ((const __attribute__((address_space(1))) void*)(p))
#define LDS(p) ((__attribute__((address_space(3))) void*)(p))

__device__ __forceinline__ short f2bf(float f) {
    __hip_bfloat16 b = __float2bfloat16(f);
    return *(short*)&b;
}
__device__ __forceinline__ float bf2f(short s) {
    __hip_bfloat16 b = *(__hip_bfloat16*)&s;
    return __bfloat162float(b);
}

// ---------------------------------------------------------------------------
// Input projection, pure-bf16 m97 structure:
// gx[(t*B + b), n] = bf16( x_bf[m=b*T+t, :608] . Wih[n, :608] + b_ih[n] )
// 128x128 tile, 256 thr = 4 waves (2x2), 4x4 16x16x32 bf16 MFMA frags/wave,
// both operands staged via global_load_lds width=16. K=608 -> 19 iters.
// ---------------------------------------------------------------------------
__global__ __launch_bounds__(256) void gemm_input(const short* __restrict__ X,
                                                  const short* __restrict__ W,
                                                  const float* __restrict__ b_ih,
                                                  short* __restrict__ gx) {
    __shared__ short sA[128 * 32];
    __shared__ short sB[128 * 32];

    const int tid  = threadIdx.x;
    const int wave = tid >> 6;
    const int lane = tid & 63;
    const int m0 = blockIdx.y * 128;
    const int n0 = blockIdx.x * 128;
    const int wm = (wave >> 1) * 64;
    const int wn = (wave & 1) * 64;

    const int srow = tid >> 2;        // staging row within a 64-row round
    const int scol = (tid & 3) * 8;
    const int fm = lane & 15;
    const int fq = lane >> 4;

    f32x4 acc[4][4] = {};

    for (int k0 = 0; k0 < IN_DP; k0 += 32) {
#pragma unroll
        for (int j = 0; j < 2; ++j) {
            const short* ga = X + (size_t)(m0 + j * 64 + srow) * IN_DP + k0 + scol;
            __builtin_amdgcn_global_load_lds(GLB(ga), LDS(sA + j * 2048 + wave * 512), 16, 0, 0);
            const short* gb = W + (size_t)(n0 + j * 64 + srow) * IN_DP + k0 + scol;
            __builtin_amdgcn_global_load_lds(GLB(gb), LDS(sB + j * 2048 + wave * 512), 16, 0, 0);
        }
        __syncthreads();

        bf16x8 af[4], bf[4];
#pragma unroll
        for (int mi = 0; mi < 4; ++mi)
            af[mi] = *(const bf16x8*)(sA + (wm + mi * 16 + fm) * 32 + fq * 8);
#pragma unroll
        for (int ni = 0; ni < 4; ++ni)
            bf[ni] = *(const bf16x8*)(sB + (wn + ni * 16 + fm) * 32 + fq * 8);
#pragma unroll
        for (int mi = 0; mi < 4; ++mi)
#pragma unroll
            for (int ni = 0; ni < 4; ++ni)
                acc[mi][ni] = __builtin_amdgcn_mfma_f32_16x16x32_bf16(af[mi], bf[ni], acc[mi][ni], 0, 0, 0);
        __syncthreads();
    }

    // D frag: row = fq*4 + r, col = fm. Write to [t][b][3H] layout.
#pragma unroll
    for (int ni = 0; ni < 4; ++ni) {
        int gn = n0 + wn + ni * 16 + fm;
        float bias = b_ih[gn];
#pragma unroll
        for (int mi = 0; mi < 4; ++mi) {
#pragma unroll
            for (int r = 0; r < 4; ++r) {
                int gm = m0 + wm + mi * 16 + fq * 4 + r;   // = b*T + t
                int b = gm / TSTEP;
                int t = gm - b * TSTEP;
                gx[((size_t)t * BATCH + b) * G3 + gn] = f2bf(acc[mi][ni][r] + bias);
            }
        }
    }
}

// ---------------------------------------------------------------------------
// Fused recurrent step: 128(batch) x 16(hidden) tile of all 3 gate
// projections gh = h @ W_hh^T, then GRU gate math + state update.
// Grid (1024/16, 2048/128) = (64, 16) = 1024 blocks (4/CU).
// 4 waves: wave w owns batch rows [w*32, w*32+32) = 2 m-frags x 3 gates.
// hb ping-pong across steps.
// ---------------------------------------------------------------------------
__global__ __launch_bounds__(256) void gru_step(const short* __restrict__ hb_in,
                                                const short* __restrict__ Whh,
                                                const short* __restrict__ gx,
                                                const float* __restrict__ b_hh,
                                                float* __restrict__ hf,
                                                short* __restrict__ hb_out,
                                                float* __restrict__ out,
                                                int t, int last) {
    __shared__ short sA[128 * 32];      // h tile
    __shared__ short sB[3 * 16 * 32];   // 3 gates x 16 rows x 32 k

    const int tid  = threadIdx.x;
    const int wave = tid >> 6;
    const int lane = tid & 63;
    const int m0 = blockIdx.y * 128;   // batch rows
    const int j0 = blockIdx.x * 16;    // hidden cols
    const int fm = lane & 15;
    const int fq = lane >> 4;

    f32x4 acc[3][2] = {};   // [gate][m-frag]

    for (int k0 = 0; k0 < HID; k0 += 32) {
        // A tile: 8 wave-units of 16 rows, 2 per wave
#pragma unroll
        for (int j = 0; j < 2; ++j) {
            int u = j * 4 + wave;
            const short* g = hb_in + (size_t)(m0 + u * 16 + (lane >> 2)) * HID + k0 + (lane & 3) * 8;
            __builtin_amdgcn_global_load_lds(GLB(g), LDS(sA + u * 512), 16, 0, 0);
        }
        // B tiles: wave w<3 stages gate w's 16 rows
        if (wave < 3) {
            const short* g = Whh + (size_t)(wave * HID + j0 + (lane >> 2)) * HID + k0 + (lane & 3) * 8;
            __builtin_amdgcn_global_load_lds(GLB(g), LDS(sB + wave * 512), 16, 0, 0);
        }
        __syncthreads();

        bf16x8 af[2], bg[3];
#pragma unroll
        for (int mi = 0; mi < 2; ++mi)
            af[mi] = *(const bf16x8*)(sA + (wave * 32 + mi * 16 + fm) * 32 + fq * 8);
#pragma unroll
        for (int g = 0; g < 3; ++g)
            bg[g] = *(const bf16x8*)(sB + g * 512 + fm * 32 + fq * 8);
#pragma unroll
        for (int g = 0; g < 3; ++g)
#pragma unroll
            for (int mi = 0; mi < 2; ++mi)
                acc[g][mi] = __builtin_amdgcn_mfma_f32_16x16x32_bf16(af[mi], bg[g], acc[g][mi], 0, 0, 0);
        __syncthreads();
    }

    // Epilogue. D frag: row = fq*4 + r, col = fm.
    const int gj = j0 + fm;
    const float bh_r = b_hh[gj];
    const float bh_i = b_hh[HID + gj];
    const float bh_n = b_hh[2 * HID + gj];
    const short* gxt = gx + (size_t)t * BATCH * G3;

#pragma unroll
    for (int mi = 0; mi < 2; ++mi) {
#pragma unroll
        for (int r = 0; r < 4; ++r) {
            int gm = m0 + wave * 32 + mi * 16 + fq * 4 + r;   // batch row
            const short* gr = gxt + (size_t)gm * G3;
            float xr = bf2f(gr[gj]);
            float xi = bf2f(gr[HID + gj]);
            float xn = bf2f(gr[2 * HID + gj]);

            float rg = 1.0f / (1.0f + __expf(-(xr + acc[0][mi][r] + bh_r)));
            float ig = 1.0f / (1.0f + __expf(-(xi + acc[1][mi][r] + bh_i)));
            float ng = tanhf(xn + rg * (acc[2][mi][r] + bh_n));

            size_t idx = (size_t)gm * HID + gj;
            float h  = hf[idx];
            float hy = ng + ig * (h - ng);
            hf[idx] = hy;
            hb_out[idx] = f2bf(hy);
            if (last) out[idx] = hy;
        }
    }
}

// x [BT,600] fp32 -> [BT,608] bf16 zero-padded
__global__ __launch_bounds__(256) void cvt_x(const float* __restrict__ X, short* __restrict__ Xb) {
    int r = blockIdx.x;
    for (int c = threadIdx.x; c < IN_DP; c += 256) {
        float v = (c < IN_D) ? X[(size_t)r * IN_D + c] : 0.f;
        Xb[(size_t)r * IN_DP + c] = f2bf(v);
    }
}

// W_ih [3072,600] fp32 -> [3072,608] bf16 zero-padded
__global__ __launch_bounds__(256) void cvt_wih(const float* __restrict__ W, short* __restrict__ Wb) {
    int r = blockIdx.x;
    for (int c = threadIdx.x; c < IN_DP; c += 256) {
        float v = (c < IN_D) ? W[(size_t)r * IN_D + c] : 0.f;
        Wb[(size_t)r * IN_DP + c] = f2bf(v);
    }
}

__global__ __launch_bounds__(256) void cvt_flat(const float* __restrict__ W, short* __restrict__ Wb, int n) {
    int i = blockIdx.x * 256 + threadIdx.x;
    if (i < n) Wb[i] = f2bf(W[i]);
}

extern "C" void kernel_launch(void* const* d_in, const int* in_sizes, int n_in,
                              void* d_out, int out_size, void* d_ws, size_t ws_size,
                              hipStream_t stream) {
    const float* x    = (const float*)d_in[0];  // [B, T, IN_D] = [BT, 600]
    const float* W_ih = (const float*)d_in[1];  // [3H, IN_D]
    const float* b_ih = (const float*)d_in[2];
    const float* W_hh = (const float*)d_in[3];  // [3H, HID]
    const float* b_hh = (const float*)d_in[4];
    float* out = (float*)d_out;                 // [B, HID]

    char* p = (char*)d_ws;
    short* gx     = (short*)p;  p += (size_t)BT * G3 * 2;       // 251.7 MB, [T][B][3H]
    short* x_bf   = (short*)p;  p += (size_t)BT * IN_DP * 2;    //  49.8 MB
    float* hf     = (float*)p;  p += (size_t)BATCH * HID * 4;   //   8.4 MB
    short* hb0    = (short*)p;  p += (size_t)BATCH * HID * 2;   //   4.2 MB
    short* hb1    = (short*)p;  p += (size_t)BATCH * HID * 2;   //   4.2 MB
    short* Wih_bf = (short*)p;  p += (size_t)G3 * IN_DP * 2;    //   3.7 MB
    short* Whh_bf = (short*)p;  p += (size_t)G3 * HID * 2;      //   6.3 MB
    // total ~328 MB

    cvt_wih<<<G3, 256, 0, stream>>>(W_ih, Wih_bf);
    cvt_flat<<<(G3 * HID + 255) / 256, 256, 0, stream>>>(W_hh, Whh_bf, G3 * HID);
    cvt_x<<<BT, 256, 0, stream>>>(x, x_bf);
    hipMemsetAsync(hf, 0, (size_t)BATCH * HID * 4, stream);
    hipMemsetAsync(hb0, 0, (size_t)BATCH * HID * 2, stream);

    // One big input projection over all timesteps: M = 40960
    dim3 igrid(G3 / 128, BT / 128);   // (24, 320)
    gemm_input<<<igrid, 256, 0, stream>>>(x_bf, Wih_bf, b_ih, gx);

    // 20 fused recurrent steps
    dim3 rgrid(HID / 16, BATCH / 128);  // (64, 16) = 1024 blocks
    for (int t = 0; t < TSTEP; ++t) {
        const short* hin = (t & 1) ? hb1 : hb0;
        short* hout      = (t & 1) ? hb0 : hb1;
        gru_step<<<rgrid, 256, 0, stream>>>(hin, Whh_bf, gx, b_hh,
                                            hf, hout, out, t, t == TSTEP - 1 ? 1 : 0);
    }
}